// Round 9
// baseline (693.871 us; speedup 1.0000x reference)
//
#include <hip/hip_runtime.h>
#include <hip/hip_bf16.h>

// ---------------------------------------------------------------------------
// DGCNN-ish network, B=16, N=128, K=20.  (R9: activations stored bf16)
// Input dtype (f32 vs bf16) detected AT RUNTIME on device (flag in ws).
// Tier P (ws >= 63.5MB): PS (f32 GEMM out / T) + XC (bf16 activations) +
//   reusable bf16 weight-pack buffer. GEMM = 128x64 tile, BK=32, register-
//   double-buffered, v_mfma 16x16x32 bf16 (B loads raw bf16 shorts).
//   kNN = per-batch 128x128 Gram via MFMA + one-wave-per-row shuffle top-20.
//   SE  = se1_k (wave per (b,t)) + se2_k (wave per (b,o)).
// Storing activations bf16 is BIT-IDENTICAL to R8: consumers converted to
// bf16 at load anyway; conversion moved to the producer.
// Tier A/B: R5 fallback paths.
// ---------------------------------------------------------------------------

#define BN_ALL 2048   // B*N = 16*128
typedef __hip_bfloat16 bf16;
typedef __attribute__((ext_vector_type(8))) short short8;
typedef __attribute__((ext_vector_type(4))) float float4v;

__device__ __forceinline__ float b2f(bf16 v) { return __bfloat162float(v); }
__device__ __forceinline__ float lrelu(float v) { return v >= 0.f ? v : 0.2f * v; }
__device__ __forceinline__ short f2bs(float v) {
    bf16 h = __float2bfloat16(v);
    return *reinterpret_cast<short*>(&h);
}

// dual-dtype input load: isb=1 -> bf16, isb=0 -> f32
__device__ __forceinline__ float ldin(const void* p, size_t i, int isb) {
    return isb ? __bfloat162float(((const bf16*)p)[i]) : ((const float*)p)[i];
}

__device__ __forceinline__ float ld1(const float* p) { return *p; }
__device__ __forceinline__ float ld1(const bf16* p)  { return __bfloat162float(*p); }
__device__ __forceinline__ void st1(float* p, float v) { *p = v; }
__device__ __forceinline__ void st1(bf16* p, float v)  { *p = __float2bfloat16(v); }
// load-as-bf16-short (for MFMA staging): f32 -> convert, bf16 -> raw
__device__ __forceinline__ short ldbs(const float* p) { return f2bs(*p); }
__device__ __forceinline__ short ldbs(const bf16* p)  { return *(const short*)p; }

// ---- dtype detection: sample 4096 dwords of x; f32 data -> sane exponents ---
__global__ __launch_bounds__(256) void detect_dtype(const void* __restrict__ x, int* __restrict__ flag) {
    const unsigned* u = (const unsigned*)x;
    int sane = 0;
    for (int i = threadIdx.x; i < 4096; i += 256) {
        unsigned e = (u[i] >> 23) & 0xFF;
        sane += (e >= 87 && e <= 167) ? 1 : 0;   // |v| in [2^-40, 2^40]
    }
    __shared__ int sh[256];
    sh[threadIdx.x] = sane;
    __syncthreads();
    for (int off = 128; off > 0; off >>= 1) {
        if (threadIdx.x < off) sh[threadIdx.x] += sh[threadIdx.x + off];
        __syncthreads();
    }
    if (threadIdx.x == 0) *flag = (sh[0] < 2048) ? 1 : 0;   // 1 = bf16, 0 = f32
}

// ---- convert input x (B,C,N) -> X (C, B*N) storage S ------------------------
template <typename S>
__global__ __launch_bounds__(256) void convert_x(const void* __restrict__ x, S* __restrict__ X0,
                                                 const int* __restrict__ dflag) {
    int isb = *dflag;
    int tid = blockIdx.x * 256 + threadIdx.x;   // tid = c*2048 + bn
    int c = tid >> 11, bn = tid & 2047;
    int b = bn >> 7, n = bn & 127;
    st1(X0 + tid, ldin(x, (size_t)(b * 512 + c) * 128 + n, isb));
}

// ---- Gram: G[b][n][m] = sum_c X[c][b*128+n] * X[c][b*128+m] (bf16 MFMA) -----
template <typename BT>
__global__ __launch_bounds__(256) void gram_k(const BT* __restrict__ X, int C,
                                              float* __restrict__ G) {
    __shared__ short Bsm[2][4096];   // 32 k x 128 points
    int tid = threadIdx.x;
    int b = blockIdx.x;
    int lane = tid & 63, wv = tid >> 6, wm = wv & 1, wn = wv >> 1;
    int lq = lane >> 4, lr = lane & 15;
    int KC = C >> 5;

    float4v acc[4][4];
#pragma unroll
    for (int i = 0; i < 4; i++)
#pragma unroll
        for (int j = 0; j < 4; j++) acc[i][j] = (float4v){0.f, 0.f, 0.f, 0.f};

    short br[2][8];
#pragma unroll
    for (int it = 0; it < 2; ++it) {
        int i = tid + it * 256;
        int q = i >> 7, c = i & 127;
        const BT* xp = X + (size_t)(q * 8) * BN_ALL + b * 128 + c;
        short8 pk;
#pragma unroll
        for (int j = 0; j < 8; ++j) pk[j] = ldbs(xp + (size_t)j * BN_ALL);
        *(short8*)&Bsm[0][(size_t)i * 8] = pk;
    }
    __syncthreads();

    int p = 0;
    for (int kc = 0; kc < KC; ++kc) {
        if (kc + 1 < KC) {
#pragma unroll
            for (int it = 0; it < 2; ++it) {
                int i = tid + it * 256;
                int q = i >> 7, c = i & 127;
                const BT* xp = X + (size_t)((kc + 1) * 32 + q * 8) * BN_ALL + b * 128 + c;
#pragma unroll
                for (int j = 0; j < 8; ++j) br[it][j] = ldbs(xp + (size_t)j * BN_ALL);
            }
        }
        short8 av[4], bv[4];
#pragma unroll
        for (int mt = 0; mt < 4; ++mt)
            av[mt] = *(const short8*)&Bsm[p][(size_t)((lq << 7) + wm * 64 + mt * 16 + lr) * 8];
#pragma unroll
        for (int nt = 0; nt < 4; ++nt)
            bv[nt] = *(const short8*)&Bsm[p][(size_t)((lq << 7) + wn * 64 + nt * 16 + lr) * 8];
#pragma unroll
        for (int mt = 0; mt < 4; ++mt)
#pragma unroll
            for (int nt = 0; nt < 4; ++nt)
                acc[mt][nt] = __builtin_amdgcn_mfma_f32_16x16x32_bf16(av[mt], bv[nt], acc[mt][nt], 0, 0, 0);
        if (kc + 1 < KC) {
#pragma unroll
            for (int it = 0; it < 2; ++it) {
                short8 pk;
#pragma unroll
                for (int j = 0; j < 8; ++j) pk[j] = br[it][j];
                *(short8*)&Bsm[p ^ 1][(size_t)(tid + it * 256) * 8] = pk;
            }
        }
        __syncthreads();
        p ^= 1;
    }

    float* Gb = G + (size_t)b * 16384;
#pragma unroll
    for (int mt = 0; mt < 4; ++mt)
#pragma unroll
        for (int r = 0; r < 4; ++r) {
            int row = wm * 64 + mt * 16 + lq * 4 + r;
#pragma unroll
            for (int nt = 0; nt < 4; ++nt) {
                int col = wn * 64 + nt * 16 + lr;
                Gb[row * 128 + col] = acc[mt][nt][r];
            }
        }
}

// ---- top-20 from Gram: one wave per (b,n) row; ties -> lower index ----------
__global__ __launch_bounds__(256) void topk_k(const float* __restrict__ G, int* __restrict__ idx) {
    int gw = (blockIdx.x * 256 + threadIdx.x) >> 6;   // 0..2047 = b*128+n
    int lane = threadIdx.x & 63;
    int b = gw >> 7, n = gw & 127;
    const float* Gb = G + (size_t)b * 16384;
    float g0 = Gb[n * 128 + lane];
    float g1 = Gb[n * 128 + 64 + lane];
    float dnn = Gb[n * 129];
    float dm0 = Gb[lane * 129];
    float dm1 = Gb[(64 + lane) * 129];
    float d0 = 2.f * g0 - dnn - dm0;
    float d1 = 2.f * g1 - dnn - dm1;
#pragma unroll
    for (int k = 0; k < 20; ++k) {
        float v; int i;
        if (d1 > d0) { v = d1; i = 64 + lane; } else { v = d0; i = lane; }
#pragma unroll
        for (int off = 1; off < 64; off <<= 1) {
            float ov = __shfl_xor(v, off, 64);
            int   oi = __shfl_xor(i, off, 64);
            if (ov > v || (ov == v && oi < i)) { v = ov; i = oi; }
        }
        if (lane == 0) idx[gw * 20 + k] = i;
        if (i < 64) { if (lane == i) d0 = -3.0e38f; }
        else        { if (lane == i - 64) d1 = -3.0e38f; }
    }
}

// ---- legacy kNN (fallback tiers) --------------------------------------------
template <typename S>
__global__ __launch_bounds__(128) void knn_topk(const S* __restrict__ X, int C, int* __restrict__ idx) {
    int b = blockIdx.x >> 7;
    int n = blockIdx.x & 127;
    int m = threadIdx.x;
    const S* base = X + b * 128;
    float s0 = 0, s1 = 0, q0 = 0, q1 = 0;
    for (int c = 0; c < C; c += 2) {
        const S* p = base + (size_t)c * BN_ALL;
        float xm0 = ld1(p + m),          xn0 = ld1(p + n);
        float xm1 = ld1(p + BN_ALL + m), xn1 = ld1(p + BN_ALL + n);
        s0 += xm0 * xn0; q0 += xm0 * xm0;
        s1 += xm1 * xn1; q1 += xm1 * xm1;
    }
    float inner = s0 + s1;
    float xxm   = q0 + q1;
    __shared__ float xx[128];
    __shared__ float dist[128];
    __shared__ float rv[128];
    __shared__ int   ri[128];
    xx[m] = xxm;
    __syncthreads();
    dist[m] = 2.0f * inner - xx[n] - xxm;
    for (int k = 0; k < 20; k++) {
        __syncthreads();
        rv[m] = dist[m]; ri[m] = m;
        __syncthreads();
        for (int off = 64; off > 0; off >>= 1) {
            if (m < off) {
                float a = rv[m], bv = rv[m + off];
                int ia = ri[m], ib = ri[m + off];
                if (bv > a || (bv == a && ib < ia)) { rv[m] = bv; ri[m] = ib; }
            }
            __syncthreads();
        }
        if (m == 0) { idx[blockIdx.x * 20 + k] = ri[0]; dist[ri[0]] = -3.0e38f; }
    }
}

// ---- weight prepack: f32/bf16 weights -> bf16 in LDS-tile image -------------
__global__ __launch_bounds__(256) void pack_w(const void* __restrict__ w, int ldw,
                                              const void* __restrict__ res, int Cin, int O,
                                              int Mtot, int K, short* __restrict__ out,
                                              const int* __restrict__ dflag) {
    int isb = *dflag;
    int item = blockIdx.x * 256 + threadIdx.x;
    if (item >= Mtot * (K >> 3)) return;
    int m_local = item & 127;
    int rest = item >> 7;            // (tm*KC + kc)*4 + q
    int q = rest & 3; rest >>= 2;
    int KC = K >> 5;
    int kc = rest % KC, tm = rest / KC;
    int grow = tm * 128 + m_local;
    int k = kc * 32 + q * 8;
    const void* src; size_t base; int dif = 0;
    if (grow < O)          { src = w;   base = (size_t)grow * ldw + k; }
    else if (grow < 2 * O) { src = w;   base = (size_t)(grow - O) * ldw + k; dif = 1; }
    else                   { src = res; base = (size_t)(grow - 2 * O) * Cin + k; }
    short8 pk;
#pragma unroll
    for (int j = 0; j < 8; ++j) {
        float v = ldin(src, base + j, isb);
        if (dif) v = ldin(src, base + Cin + j, isb) - v;
        pk[j] = f2bs(v);
    }
    *(short8*)&out[(size_t)item * 8] = pk;
}

// ---- packed-A bf16 MFMA GEMM, 128x64 tile, BK=32, register double-buffer ----
// B operand type BT (f32 or bf16 storage), C output type CT.
template <typename BT, typename CT>
__global__ __launch_bounds__(256) void gemm_pk(const short* __restrict__ packA,
                                               const BT* __restrict__ X, CT* __restrict__ Cm, int K,
                                               const void* __restrict__ bnS, const void* __restrict__ bnB,
                                               int act, const int* __restrict__ dflag) {
    __shared__ short Asm[2][4096];   // 128 rows x 32 k (bf16)
    __shared__ short Bsm[2][2048];   // 32 k x 64 cols
    int tid = threadIdx.x;
    int bm  = blockIdx.x << 7;
    int bn0 = blockIdx.y << 6;
    int lane = tid & 63, wv = tid >> 6, wm = wv & 1, wn = wv >> 1;
    int lq = lane >> 4, lr = lane & 15;
    int KC = K >> 5;
    const short* abase = packA + (size_t)blockIdx.x * KC * 4096;

    float4v acc[4][2];
#pragma unroll
    for (int i = 0; i < 4; i++)
#pragma unroll
        for (int j = 0; j < 2; j++) acc[i][j] = (float4v){0.f, 0.f, 0.f, 0.f};

    short8 ar[2];
    short  br[8];
    int bq = tid >> 6, bc = tid & 63;

#pragma unroll
    for (int it = 0; it < 2; ++it)
        ar[it] = *(const short8*)&abase[(size_t)(tid + it * 256) * 8];
    {
        const BT* xp = X + (size_t)(bq * 8) * BN_ALL + bn0 + bc;
#pragma unroll
        for (int j = 0; j < 8; ++j) br[j] = ldbs(xp + (size_t)j * BN_ALL);
    }
#pragma unroll
    for (int it = 0; it < 2; ++it)
        *(short8*)&Asm[0][(size_t)(tid + it * 256) * 8] = ar[it];
    {
        short8 pk;
#pragma unroll
        for (int j = 0; j < 8; ++j) pk[j] = br[j];
        *(short8*)&Bsm[0][(size_t)tid * 8] = pk;
    }
    __syncthreads();

    int p = 0;
    for (int kc = 0; kc < KC; ++kc) {
        if (kc + 1 < KC) {
            const short* ab = abase + (size_t)(kc + 1) * 4096;
#pragma unroll
            for (int it = 0; it < 2; ++it)
                ar[it] = *(const short8*)&ab[(size_t)(tid + it * 256) * 8];
            const BT* xp = X + (size_t)((kc + 1) * 32 + bq * 8) * BN_ALL + bn0 + bc;
#pragma unroll
            for (int j = 0; j < 8; ++j) br[j] = ldbs(xp + (size_t)j * BN_ALL);
        }
        short8 av[4], bv[2];
#pragma unroll
        for (int mt = 0; mt < 4; ++mt)
            av[mt] = *(const short8*)&Asm[p][(size_t)((lq << 7) + wm * 64 + mt * 16 + lr) * 8];
#pragma unroll
        for (int nt = 0; nt < 2; ++nt)
            bv[nt] = *(const short8*)&Bsm[p][(size_t)((lq << 6) + wn * 32 + nt * 16 + lr) * 8];
#pragma unroll
        for (int mt = 0; mt < 4; ++mt)
#pragma unroll
            for (int nt = 0; nt < 2; ++nt)
                acc[mt][nt] = __builtin_amdgcn_mfma_f32_16x16x32_bf16(av[mt], bv[nt], acc[mt][nt], 0, 0, 0);
        if (kc + 1 < KC) {
#pragma unroll
            for (int it = 0; it < 2; ++it)
                *(short8*)&Asm[p ^ 1][(size_t)(tid + it * 256) * 8] = ar[it];
            short8 pk;
#pragma unroll
            for (int j = 0; j < 8; ++j) pk[j] = br[j];
            *(short8*)&Bsm[p ^ 1][(size_t)tid * 8] = pk;
        }
        __syncthreads();
        p ^= 1;
    }

    int isb = *dflag;
#pragma unroll
    for (int mt = 0; mt < 4; ++mt) {
#pragma unroll
        for (int r = 0; r < 4; ++r) {
            int row = bm + wm * 64 + mt * 16 + lq * 4 + r;
            float s = 1.f, bb = 0.f;
            if (bnS) { s = ldin(bnS, row, isb); bb = ldin(bnB, row, isb); }
#pragma unroll
            for (int nt = 0; nt < 2; ++nt) {
                int col = bn0 + wn * 32 + nt * 16 + lr;
                float v = acc[mt][nt][r];
                if (bnS) v = v * s + bb;
                if (act) v = lrelu(v);
                st1(Cm + (size_t)row * BN_ALL + col, v);
            }
        }
    }
}

// ---- R5 fallback GEMM (on-the-fly staging, 128x128) -------------------------
template <typename S>
__global__ __launch_bounds__(256) void gemm_mfma(const void* __restrict__ w, int ldw,
                                                 const void* __restrict__ res, int Cin, int O,
                                                 const S* __restrict__ X, S* __restrict__ Cm, int K,
                                                 const void* __restrict__ bnS, const void* __restrict__ bnB,
                                                 int act, const int* __restrict__ dflag) {
    int isb = *dflag;
    __shared__ short Asm[4096];
    __shared__ short Bsm[4096];
    int tid = threadIdx.x;
    int bm  = blockIdx.x << 7;
    int bn0 = blockIdx.y << 7;
    int lane = tid & 63, wv = tid >> 6;
    int wm = wv & 1, wn = wv >> 1;
    int lq = lane >> 4, lr = lane & 15;

    float4v acc[4][4];
#pragma unroll
    for (int i = 0; i < 4; i++)
#pragma unroll
        for (int j = 0; j < 4; j++) acc[i][j] = (float4v){0.f, 0.f, 0.f, 0.f};

    for (int k0 = 0; k0 < K; k0 += 32) {
#pragma unroll
        for (int it = 0; it < 2; ++it) {
            int i = tid + it * 256;
            int m = i >> 2, q = i & 3;
            int grow = bm + m;
            const void* asrc; size_t abase; int dif = 0;
            if (grow < O)          { asrc = w;   abase = (size_t)grow * ldw; }
            else if (grow < 2 * O) { asrc = w;   abase = (size_t)(grow - O) * ldw; dif = 1; }
            else                   { asrc = res; abase = (size_t)(grow - 2 * O) * Cin; }
            size_t kk = (size_t)k0 + q * 8;
            short8 pk;
#pragma unroll
            for (int j = 0; j < 8; ++j) {
                float v = ldin(asrc, abase + kk + j, isb);
                if (dif) v = ldin(asrc, abase + Cin + kk + j, isb) - v;
                pk[j] = f2bs(v);
            }
            *(short8*)&Asm[(size_t)(q * 128 + m) * 8] = pk;
        }
#pragma unroll
        for (int it = 0; it < 2; ++it) {
            int i = tid + it * 256;
            int q = i >> 7, c = i & 127;
            const S* xp = X + (size_t)(k0 + q * 8) * BN_ALL + bn0 + c;
            short8 pk;
#pragma unroll
            for (int j = 0; j < 8; ++j) pk[j] = f2bs(ld1(xp + (size_t)j * BN_ALL));
            *(short8*)&Bsm[(size_t)i * 8] = pk;
        }
        __syncthreads();
        short8 av[4], bv[4];
#pragma unroll
        for (int mt = 0; mt < 4; ++mt)
            av[mt] = *(const short8*)&Asm[(size_t)((lq << 7) + wm * 64 + mt * 16 + lr) * 8];
#pragma unroll
        for (int nt = 0; nt < 4; ++nt)
            bv[nt] = *(const short8*)&Bsm[(size_t)((lq << 7) + wn * 64 + nt * 16 + lr) * 8];
#pragma unroll
        for (int mt = 0; mt < 4; ++mt)
#pragma unroll
            for (int nt = 0; nt < 4; ++nt)
                acc[mt][nt] = __builtin_amdgcn_mfma_f32_16x16x32_bf16(av[mt], bv[nt], acc[mt][nt], 0, 0, 0);
        __syncthreads();
    }
#pragma unroll
    for (int mt = 0; mt < 4; ++mt) {
#pragma unroll
        for (int r = 0; r < 4; ++r) {
            int row = bm + wm * 64 + mt * 16 + lq * 4 + r;
            float s = 1.f, bb = 0.f;
            if (bnS) { s = ldin(bnS, row, isb); bb = ldin(bnB, row, isb); }
#pragma unroll
            for (int nt = 0; nt < 4; ++nt) {
                int col = bn0 + wn * 64 + nt * 16 + lr;
                float v = acc[mt][nt][r];
                if (bnS) v = v * s + bb;
                if (act) v = lrelu(v);
                st1(Cm + (size_t)row * BN_ALL + col, v);
            }
        }
    }
}

// ---- gather + k-pool + bn + lrelu; T written IN-PLACE over P row o ----------
template <typename S>
__global__ __launch_bounds__(128) void gather_pool(S* __restrict__ PS, const int* __restrict__ idx,
                                                   const void* __restrict__ bns, const void* __restrict__ bnb,
                                                   float* __restrict__ Mb, int O,
                                                   const int* __restrict__ dflag) {
    int isb = *dflag;
    int o = blockIdx.x, b = blockIdx.y, n = threadIdx.x;
    S* Prow = PS + (size_t)o * BN_ALL + b * 128;
    const int* id = idx + (b * 128 + n) * 20;
    float mx = -3.0e38f, mn = 3.0e38f, sm = 0.f;
#pragma unroll
    for (int k = 0; k < 20; k++) {
        float p = ld1(Prow + id[k]);
        mx = fmaxf(mx, p); mn = fminf(mn, p); sm += p;
    }
    float Sv = ld1(PS + (size_t)(O + o) * BN_ALL + b * 128 + n);
    __shared__ float r1[128], r2[128];
    r1[n] = sm; r2[n] = Sv;
    __syncthreads();                       // all P reads complete before overwrite
    float s = ldin(bns, o, isb), bb = ldin(bnb, o, isb);
    float ext = (s >= 0.f) ? mx : mn;
    st1(Prow + n, lrelu(s * (ext + Sv) + bb));   // T row o (aliases P row o)
    for (int off = 64; off > 0; off >>= 1) {
        if (n < off) { r1[n] += r1[n + off]; r2[n] += r2[n + off]; }
        __syncthreads();
    }
    if (n == 0) Mb[b * O + o] = s * (r1[0] * (1.f / 2560.f) + r2[0] * (1.f / 128.f)) + bb;
}

// ---- SE stage 1: z[b,t] = relu(w1[t,:] . M[b,:]) — one wave per (b,t) -------
__global__ __launch_bounds__(256) void se1_k(const float* __restrict__ Mb, const void* __restrict__ w1,
                                             float* __restrict__ Z, int O, int r,
                                             const int* __restrict__ dflag) {
    int isb = *dflag;
    int gw = (blockIdx.x * 256 + threadIdx.x) >> 6;   // b*r + t
    int lane = threadIdx.x & 63;
    int b = gw / r, t = gw - b * r;
    const float* mv = Mb + (size_t)b * O;
    float acc = 0.f;
    for (int c = lane; c < O; c += 64) acc += ldin(w1, (size_t)t * O + c, isb) * mv[c];
#pragma unroll
    for (int off = 32; off > 0; off >>= 1) acc += __shfl_xor(acc, off, 64);
    if (lane == 0) Z[b * r + t] = fmaxf(acc, 0.f);
}

// ---- SE stage 2: Y[b,o] = sigmoid(w2[o,:] . z[b,:]) — one wave per (b,o) ----
__global__ __launch_bounds__(256) void se2_k(const float* __restrict__ Z, const void* __restrict__ w2,
                                             float* __restrict__ Y, int O, int r,
                                             const int* __restrict__ dflag) {
    int isb = *dflag;
    int gw = (blockIdx.x * 256 + threadIdx.x) >> 6;   // b*O + o
    int lane = threadIdx.x & 63;
    int b = gw / O, o = gw - b * O;
    float acc = 0.f;
    if (lane < r) acc = ldin(w2, (size_t)o * r + lane, isb) * Z[b * r + lane];
#pragma unroll
    for (int off = 32; off > 0; off >>= 1) acc += __shfl_xor(acc, off, 64);
    if (lane == 0) Y[b * O + o] = 1.f / (1.f + expf(-acc));
}

// ---- legacy SE (fallback tiers) ---------------------------------------------
__global__ __launch_bounds__(256) void se_k(const float* __restrict__ Mb, const void* __restrict__ w1,
                                            const void* __restrict__ w2, float* __restrict__ Y, int O, int r,
                                            const int* __restrict__ dflag) {
    int isb = *dflag;
    int b = blockIdx.x, t = threadIdx.x;
    __shared__ float mloc[1024];
    __shared__ float z[64];
    for (int i = t; i < O; i += 256) mloc[i] = Mb[b * O + i];
    __syncthreads();
    if (t < r) {
        float acc = 0.f;
        for (int c = 0; c < O; c++) acc += ldin(w1, (size_t)t * O + c, isb) * mloc[c];
        z[t] = fmaxf(acc, 0.f);
    }
    __syncthreads();
    for (int o = t; o < O; o += 256) {
        float acc = 0.f;
        for (int j = 0; j < r; j++) acc += ldin(w2, (size_t)o * r + j, isb) * z[j];
        Y[b * O + o] = 1.f / (1.f + expf(-acc));
    }
}

// ---- finalize: x_next = y * T (+ residual rows) -> XC slice -----------------
template <typename SP, typename SD>
__global__ __launch_bounds__(256) void finalize(const SP* __restrict__ PS, const float* __restrict__ Y,
                                                int useR, SD* __restrict__ Xdst, int O) {
    int tid = blockIdx.x * 256 + threadIdx.x;   // tid = o*2048 + bn
    int o = tid >> 11, bn = tid & 2047;
    int b = bn >> 7;
    float v = Y[b * O + o] * ld1(PS + tid);     // T row o, col bn
    if (useR) v += ld1(PS + (size_t)(2 * O + o) * BN_ALL + bn);
    st1(Xdst + tid, v);
}

// ---- conv5 pool: f[b, m] = max_n, f[b, 2048+m] = mean_n ---------------------
template <typename S>
__global__ __launch_bounds__(128) void pool5(const S* __restrict__ H, float* __restrict__ f) {
    int m = blockIdx.x, b = blockIdx.y, n = threadIdx.x;
    float v = ld1(H + (size_t)m * BN_ALL + b * 128 + n);
    __shared__ float rmx[128], rsm[128];
    rmx[n] = v; rsm[n] = v;
    __syncthreads();
    for (int off = 64; off > 0; off >>= 1) {
        if (n < off) { rmx[n] = fmaxf(rmx[n], rmx[n + off]); rsm[n] += rsm[n + off]; }
        __syncthreads();
    }
    if (n == 0) {
        f[b * 4096 + m] = rmx[0];
        f[b * 4096 + 2048 + m] = rsm[0] * (1.f / 128.f);
    }
}

// ---- head: one wave per (b,o) dot product + optional bias/bn/lrelu ----------
__global__ __launch_bounds__(256) void head_k(const float* __restrict__ in, const void* __restrict__ W,
                                              const void* __restrict__ bias, const void* __restrict__ bns,
                                              const void* __restrict__ bnb, float* __restrict__ outf,
                                              void* __restrict__ outb, int Kd, int Od, int act,
                                              const int* __restrict__ dflag) {
    int isb = *dflag;
    int gw = (blockIdx.x * 256 + threadIdx.x) >> 6;
    int lane = threadIdx.x & 63;
    if (gw >= 16 * Od) return;
    int b = gw / Od, o = gw - b * Od;
    const float* iv = in + b * Kd;
    float acc = 0.f;
    for (int k = lane; k < Kd; k += 64) acc += iv[k] * ldin(W, (size_t)o * Kd + k, isb);
    for (int off = 32; off > 0; off >>= 1) acc += __shfl_xor(acc, off, 64);
    if (lane == 0) {
        float v = acc;
        if (bias) v += ldin(bias, o, isb);
        if (bns) v = v * ldin(bns, o, isb) + ldin(bnb, o, isb);
        if (act) v = lrelu(v);
        if (outb) {
            if (isb) ((bf16*)outb)[gw] = __float2bfloat16(v);
            else     ((float*)outb)[gw] = v;
        } else outf[gw] = v;
    }
}

// ---- ws-too-small signal ----------------------------------------------------
__global__ __launch_bounds__(256) void zero_out(bf16* o, int n) {
    int i = blockIdx.x * 256 + threadIdx.x;
    if (i < n) o[i] = __float2bfloat16(0.f);
}

// ---------------------------------------------------------------------------
#define UNPACK_INPUTS()                                                     \
    const void* x_in   = d_in[0];                                           \
    const void* conv1w = d_in[1];  const void* conv2w = d_in[2];            \
    const void* conv3w = d_in[3];  const void* conv4w = d_in[4];            \
    const void* conv5w = d_in[5];                                           \
    const void* bn1s = d_in[6],  * bn1b = d_in[7];                          \
    const void* bn2s = d_in[8],  * bn2b = d_in[9];                          \
    const void* bn3s = d_in[10], * bn3b = d_in[11];                         \
    const void* bn4s = d_in[12], * bn4b = d_in[13];                         \
    const void* bn5s = d_in[14], * bn5b = d_in[15];                         \
    const void* se1w1 = d_in[16], * se1w2 = d_in[17];                       \
    const void* se2w1 = d_in[18], * se2w2 = d_in[19];                       \
    const void* se3w1 = d_in[20], * se3w2 = d_in[21];                       \
    const void* se4w1 = d_in[22], * se4w2 = d_in[23];                       \
    const void* res1w = d_in[24]; const void* res2w = d_in[25];             \
    const void* res3w = d_in[26]; const void* lin1w = d_in[27];             \
    const void* bn6s = d_in[28], * bn6b = d_in[29];                         \
    const void* lin2w = d_in[30], * lin2b = d_in[31];                       \
    const void* bn7s = d_in[32], * bn7b = d_in[33];                         \
    const void* lin3w = d_in[34], * lin3b = d_in[35];

// ---- Tier P: packed weights, f32 PS, bf16 XC --------------------------------
static void run_net_packed(void* const* d_in, void* d_out, void* d_ws, hipStream_t stream) {
    UNPACK_INPUTS();
    float* WS = (float*)d_ws;
    float* PS   = WS;                              // 3072 x 2048 f32 (gemm out / T / conv5 H)
    bf16*  XC   = (bf16*)(WS + 6291456);           // 3072 x 2048 bf16 (x1|x2|x3|x4)
    short* PACK = (short*)(WS + 12582912);         // up to 6,291,456 shorts
    float* MB = WS + 15728640;
    float* YB = MB + 16384;
    float* FB = YB + 16384;
    float* F1 = FB + 65536;
    float* F2 = F1 + 8192;
    int* IDX  = (int*)(F2 + 4096);
    int* DFLAG = IDX + 40960;
    float* ZB = (float*)(DFLAG + 16);              // 1024 floats
    bf16*  X0 = (bf16*)(PS + (size_t)2048 * BN_ALL);  // PS rows 2048.. (block 1 only)
    float* GRAM = PS;                              // PS rows 0..127 during kNN
    bf16* X1 = XC;
    bf16* X2 = XC + (size_t)512 * BN_ALL;
    bf16* X3 = XC + (size_t)1024 * BN_ALL;
    bf16* X4 = XC + (size_t)2048 * BN_ALL;

    detect_dtype<<<1, 256, 0, stream>>>(x_in, DFLAG);
    convert_x<bf16><<<4096, 256, 0, stream>>>(x_in, X0, DFLAG);

    // block 1: Cin=512, O=512, Mtot=1024, K=512, r=32
    gram_k<bf16><<<16, 256, 0, stream>>>(X0, 512, GRAM);
    topk_k<<<512, 256, 0, stream>>>(GRAM, IDX);
    pack_w<<<256, 256, 0, stream>>>(conv1w, 1024, nullptr, 512, 512, 1024, 512, PACK, DFLAG);
    gemm_pk<bf16, float><<<dim3(8, 32), 256, 0, stream>>>(PACK, X0, PS, 512, nullptr, nullptr, 0, DFLAG);
    gather_pool<float><<<dim3(512, 16), 128, 0, stream>>>(PS, IDX, bn1s, bn1b, MB, 512, DFLAG);
    se1_k<<<128, 256, 0, stream>>>(MB, se1w1, ZB, 512, 32, DFLAG);
    se2_k<<<2048, 256, 0, stream>>>(ZB, se1w2, YB, 512, 32, DFLAG);
    finalize<float, bf16><<<4096, 256, 0, stream>>>(PS, YB, 0, X1, 512);

    // block 2: Mtot=1536, K=512, res1, r=32
    gram_k<bf16><<<16, 256, 0, stream>>>(X1, 512, GRAM);
    topk_k<<<512, 256, 0, stream>>>(GRAM, IDX);
    pack_w<<<384, 256, 0, stream>>>(conv2w, 1024, res1w, 512, 512, 1536, 512, PACK, DFLAG);
    gemm_pk<bf16, float><<<dim3(12, 32), 256, 0, stream>>>(PACK, X1, PS, 512, nullptr, nullptr, 0, DFLAG);
    gather_pool<float><<<dim3(512, 16), 128, 0, stream>>>(PS, IDX, bn2s, bn2b, MB, 512, DFLAG);
    se1_k<<<128, 256, 0, stream>>>(MB, se2w1, ZB, 512, 32, DFLAG);
    se2_k<<<2048, 256, 0, stream>>>(ZB, se2w2, YB, 512, 32, DFLAG);
    finalize<float, bf16><<<4096, 256, 0, stream>>>(PS, YB, 1, X2, 512);

    // block 3: O=1024, Mtot=3072, K=512, res2, r=64
    gram_k<bf16><<<16, 256, 0, stream>>>(X2, 512, GRAM);
    topk_k<<<512, 256, 0, stream>>>(GRAM, IDX);
    pack_w<<<768, 256, 0, stream>>>(conv3w, 1024, res2w, 512, 1024, 3072, 512, PACK, DFLAG);
    gemm_pk<bf16, float><<<dim3(24, 32), 256, 0, stream>>>(PACK, X2, PS, 512, nullptr, nullptr, 0, DFLAG);
    gather_pool<float><<<dim3(1024, 16), 128, 0, stream>>>(PS, IDX, bn3s, bn3b, MB, 1024, DFLAG);
    se1_k<<<256, 256, 0, stream>>>(MB, se3w1, ZB, 1024, 64, DFLAG);
    se2_k<<<4096, 256, 0, stream>>>(ZB, se3w2, YB, 1024, 64, DFLAG);
    finalize<float, bf16><<<8192, 256, 0, stream>>>(PS, YB, 1, X3, 1024);

    // block 4: O=1024, Mtot=3072, K=1024, res3, r=64
    gram_k<bf16><<<16, 256, 0, stream>>>(X3, 1024, GRAM);
    topk_k<<<512, 256, 0, stream>>>(GRAM, IDX);
    pack_w<<<1536, 256, 0, stream>>>(conv4w, 2048, res3w, 1024, 1024, 3072, 1024, PACK, DFLAG);
    gemm_pk<bf16, float><<<dim3(24, 32), 256, 0, stream>>>(PACK, X3, PS, 1024, nullptr, nullptr, 0, DFLAG);
    gather_pool<float><<<dim3(1024, 16), 128, 0, stream>>>(PS, IDX, bn4s, bn4b, MB, 1024, DFLAG);
    se1_k<<<256, 256, 0, stream>>>(MB, se4w1, ZB, 1024, 64, DFLAG);
    se2_k<<<4096, 256, 0, stream>>>(ZB, se4w2, YB, 1024, 64, DFLAG);
    finalize<float, bf16><<<8192, 256, 0, stream>>>(PS, YB, 1, X4, 1024);

    // conv5: Mtot=2048, K=3072, bn5+lrelu
    pack_w<<<3072, 256, 0, stream>>>(conv5w, 3072, nullptr, 3072, 2048, 2048, 3072, PACK, DFLAG);
    gemm_pk<bf16, float><<<dim3(16, 32), 256, 0, stream>>>(PACK, XC, PS, 3072, bn5s, bn5b, 1, DFLAG);
    pool5<float><<<dim3(2048, 16), 128, 0, stream>>>(PS, FB);

    head_k<<<2048, 256, 0, stream>>>(FB, lin1w, nullptr, bn6s, bn6b, F1, nullptr, 4096, 512, 1, DFLAG);
    head_k<<<1024, 256, 0, stream>>>(F1, lin2w, lin2b, bn7s, bn7b, F2, nullptr, 512, 256, 1, DFLAG);
    head_k<<<160, 256, 0, stream>>>(F2, lin3w, lin3b, nullptr, nullptr, nullptr, d_out, 256, 40, 0, DFLAG);
}

// ---- Tier A/B fallback (R5 path) --------------------------------------------
template <typename S>
static void run_net(void* const* d_in, void* d_out, void* d_ws, hipStream_t stream) {
    UNPACK_INPUTS();
    const size_t RC = (size_t)3072 * BN_ALL;
    S* PS = (S*)d_ws;
    S* XC = PS + RC;
    S* X0 = PS + (size_t)2048 * BN_ALL;
    float* MB = (float*)(XC + RC);
    float* YB = MB + 16 * 1024;
    float* FB = YB + 16 * 1024;
    float* F1 = FB + 16 * 4096;
    float* F2 = F1 + 16 * 512;
    int* IDX  = (int*)(F2 + 16 * 256);
    int* DFLAG = IDX + 16 * 128 * 20;

    S* X1 = XC;
    S* X2 = XC + (size_t)512 * BN_ALL;
    S* X3 = XC + (size_t)1024 * BN_ALL;
    S* X4 = XC + (size_t)2048 * BN_ALL;

    detect_dtype<<<1, 256, 0, stream>>>(x_in, DFLAG);
    convert_x<S><<<4096, 256, 0, stream>>>(x_in, X0, DFLAG);

    knn_topk<S><<<2048, 128, 0, stream>>>(X0, 512, IDX);
    gemm_mfma<S><<<dim3(8, 16), 256, 0, stream>>>(conv1w, 1024, nullptr, 512, 512, X0, PS, 512, nullptr, nullptr, 0, DFLAG);
    gather_pool<S><<<dim3(512, 16), 128, 0, stream>>>(PS, IDX, bn1s, bn1b, MB, 512, DFLAG);
    se_k<<<16, 256, 0, stream>>>(MB, se1w1, se1w2, YB, 512, 32, DFLAG);
    finalize<S, S><<<4096, 256, 0, stream>>>(PS, YB, 0, X1, 512);

    knn_topk<S><<<2048, 128, 0, stream>>>(X1, 512, IDX);
    gemm_mfma<S><<<dim3(12, 16), 256, 0, stream>>>(conv2w, 1024, res1w, 512, 512, X1, PS, 512, nullptr, nullptr, 0, DFLAG);
    gather_pool<S><<<dim3(512, 16), 128, 0, stream>>>(PS, IDX, bn2s, bn2b, MB, 512, DFLAG);
    se_k<<<16, 256, 0, stream>>>(MB, se2w1, se2w2, YB, 512, 32, DFLAG);
    finalize<S, S><<<4096, 256, 0, stream>>>(PS, YB, 1, X2, 512);

    knn_topk<S><<<2048, 128, 0, stream>>>(X2, 512, IDX);
    gemm_mfma<S><<<dim3(24, 16), 256, 0, stream>>>(conv3w, 1024, res2w, 512, 1024, X2, PS, 512, nullptr, nullptr, 0, DFLAG);
    gather_pool<S><<<dim3(1024, 16), 128, 0, stream>>>(PS, IDX, bn3s, bn3b, MB, 1024, DFLAG);
    se_k<<<16, 256, 0, stream>>>(MB, se3w1, se3w2, YB, 1024, 64, DFLAG);
    finalize<S, S><<<8192, 256, 0, stream>>>(PS, YB, 1, X3, 1024);

    knn_topk<S><<<2048, 128, 0, stream>>>(X3, 1024, IDX);
    gemm_mfma<S><<<dim3(24, 16), 256, 0, stream>>>(conv4w, 2048, res3w, 1024, 1024, X3, PS, 1024, nullptr, nullptr, 0, DFLAG);
    gather_pool<S><<<dim3(1024, 16), 128, 0, stream>>>(PS, IDX, bn4s, bn4b, MB, 1024, DFLAG);
    se_k<<<16, 256, 0, stream>>>(MB, se4w1, se4w2, YB, 1024, 64, DFLAG);
    finalize<S, S><<<8192, 256, 0, stream>>>(PS, YB, 1, X4, 1024);

    gemm_mfma<S><<<dim3(16, 16), 256, 0, stream>>>(conv5w, 3072, nullptr, 3072, 2048, XC, PS, 3072, bn5s, bn5b, 1, DFLAG);
    pool5<S><<<dim3(2048, 16), 128, 0, stream>>>(PS, FB);

    head_k<<<2048, 256, 0, stream>>>(FB, lin1w, nullptr, bn6s, bn6b, F1, nullptr, 4096, 512, 1, DFLAG);
    head_k<<<1024, 256, 0, stream>>>(F1, lin2w, lin2b, bn7s, bn7b, F2, nullptr, 512, 256, 1, DFLAG);
    head_k<<<160, 256, 0, stream>>>(F2, lin3w, lin3b, nullptr, nullptr, nullptr, d_out, 256, 40, 0, DFLAG);
}

extern "C" void kernel_launch(void* const* d_in, const int* in_sizes, int n_in,
                              void* d_out, int out_size, void* d_ws, size_t ws_size,
                              hipStream_t stream) {
    const size_t SMALL = (16 * 1024 + 16 * 1024 + 16 * 4096 + 16 * 512 + 16 * 256) * 4
                       + 16 * 128 * 20 * 4 + 8192;
    const size_t NEED_PACKED = (size_t)15728640 * 4 + SMALL;
    const size_t NEED_F32    = 2 * ((size_t)3072 * BN_ALL * 4) + SMALL;
    const size_t NEED_BF16   = 2 * ((size_t)3072 * BN_ALL * 2) + SMALL;
    if (ws_size >= NEED_PACKED) {
        run_net_packed(d_in, d_out, d_ws, stream);
    } else if (ws_size >= NEED_F32) {
        run_net<float>(d_in, d_out, d_ws, stream);
    } else if (ws_size >= NEED_BF16) {
        run_net<bf16>(d_in, d_out, d_ws, stream);
    } else {
        zero_out<<<3, 256, 0, stream>>>((bf16*)d_out, out_size);
    }
}

// Round 10
// 626.145 us; speedup vs baseline: 1.1082x; 1.1082x over previous
//
#include <hip/hip_runtime.h>
#include <hip/hip_bf16.h>

// ---------------------------------------------------------------------------
// DGCNN-ish network, B=16, N=128, K=20.  (R10: k-packed bf16 activations)
// Tier P: activations stored K-PACKED bf16: X'[((k/8)*2048 + col)*8 + (k&7)].
//   The global image of any 32k x 64c B-tile equals its LDS fragment image ->
//   GEMM/Gram staging = one 16-B load + one 16-B LDS write per thread, zero
//   conversions in the K-loop. PS (GEMM out / T) stays f32.
//   Producers (finalize_kp / convert_kp) pay the transpose once, coalesced.
// Bit-identical numerics to R9 (same bf16 values, same MFMA order).
// Tier A/B: R5 fallback paths (linear layouts).
// ---------------------------------------------------------------------------

#define BN_ALL 2048   // B*N = 16*128
typedef __hip_bfloat16 bf16;
typedef __attribute__((ext_vector_type(8))) short short8;
typedef __attribute__((ext_vector_type(4))) float float4v;

__device__ __forceinline__ float b2f(bf16 v) { return __bfloat162float(v); }
__device__ __forceinline__ float lrelu(float v) { return v >= 0.f ? v : 0.2f * v; }
__device__ __forceinline__ short f2bs(float v) {
    bf16 h = __float2bfloat16(v);
    return *reinterpret_cast<short*>(&h);
}

// dual-dtype input load: isb=1 -> bf16, isb=0 -> f32
__device__ __forceinline__ float ldin(const void* p, size_t i, int isb) {
    return isb ? __bfloat162float(((const bf16*)p)[i]) : ((const float*)p)[i];
}

__device__ __forceinline__ float ld1(const float* p) { return *p; }
__device__ __forceinline__ float ld1(const bf16* p)  { return __bfloat162float(*p); }
__device__ __forceinline__ void st1(float* p, float v) { *p = v; }
__device__ __forceinline__ void st1(bf16* p, float v)  { *p = __float2bfloat16(v); }
__device__ __forceinline__ short ldbs(const float* p) { return f2bs(*p); }
__device__ __forceinline__ short ldbs(const bf16* p)  { return *(const short*)p; }

// ---- dtype detection: sample 4096 dwords of x; f32 data -> sane exponents ---
__global__ __launch_bounds__(256) void detect_dtype(const void* __restrict__ x, int* __restrict__ flag) {
    const unsigned* u = (const unsigned*)x;
    int sane = 0;
    for (int i = threadIdx.x; i < 4096; i += 256) {
        unsigned e = (u[i] >> 23) & 0xFF;
        sane += (e >= 87 && e <= 167) ? 1 : 0;   // |v| in [2^-40, 2^40]
    }
    __shared__ int sh[256];
    sh[threadIdx.x] = sane;
    __syncthreads();
    for (int off = 128; off > 0; off >>= 1) {
        if (threadIdx.x < off) sh[threadIdx.x] += sh[threadIdx.x + off];
        __syncthreads();
    }
    if (threadIdx.x == 0) *flag = (sh[0] < 2048) ? 1 : 0;   // 1 = bf16, 0 = f32
}

// ---- convert input x (B,C,N) -> X0 k-packed bf16 ----------------------------
__global__ __launch_bounds__(256) void convert_kp(const void* __restrict__ x, bf16* __restrict__ X0,
                                                  const int* __restrict__ dflag) {
    int isb = *dflag;
    int item = blockIdx.x * 256 + threadIdx.x;   // cg*2048 + bn  (cg = c/8)
    int cg = item >> 11, bn = item & 2047;
    int b = bn >> 7, n = bn & 127;
    short8 pk;
#pragma unroll
    for (int j = 0; j < 8; ++j)
        pk[j] = f2bs(ldin(x, ((size_t)(b * 512 + cg * 8 + j)) * 128 + n, isb));
    *(short8*)((short*)X0 + ((size_t)cg * BN_ALL + bn) * 8) = pk;
}

// ---- Gram via MFMA from k-packed X; one block per batch ---------------------
__global__ __launch_bounds__(256) void gram_k(const bf16* __restrict__ X, int C,
                                              float* __restrict__ G) {
    __shared__ short Bsm[2][4096];   // image [(q*128 + point)*8 + j]
    int tid = threadIdx.x;
    int b = blockIdx.x;
    int lane = tid & 63, wv = tid >> 6, wm = wv & 1, wn = wv >> 1;
    int lq = lane >> 4, lr = lane & 15;
    int KC = C >> 5;
    const short* Xs = (const short*)X;

    float4v acc[4][4];
#pragma unroll
    for (int i = 0; i < 4; i++)
#pragma unroll
        for (int j = 0; j < 4; j++) acc[i][j] = (float4v){0.f, 0.f, 0.f, 0.f};

    short8 br2[2];
#pragma unroll
    for (int it = 0; it < 2; ++it) {
        int i = tid + it * 256;
        int q = i >> 7, c = i & 127;
        *(short8*)&Bsm[0][(size_t)i * 8] =
            *(const short8*)(Xs + ((size_t)q * BN_ALL + b * 128 + c) * 8);
    }
    __syncthreads();

    int p = 0;
    for (int kc = 0; kc < KC; ++kc) {
        if (kc + 1 < KC) {
#pragma unroll
            for (int it = 0; it < 2; ++it) {
                int i = tid + it * 256;
                int q = i >> 7, c = i & 127;
                br2[it] = *(const short8*)(Xs + ((size_t)((kc + 1) * 4 + q) * BN_ALL + b * 128 + c) * 8);
            }
        }
        short8 av[4], bv[4];
#pragma unroll
        for (int mt = 0; mt < 4; ++mt)
            av[mt] = *(const short8*)&Bsm[p][(size_t)((lq << 7) + wm * 64 + mt * 16 + lr) * 8];
#pragma unroll
        for (int nt = 0; nt < 4; ++nt)
            bv[nt] = *(const short8*)&Bsm[p][(size_t)((lq << 7) + wn * 64 + nt * 16 + lr) * 8];
#pragma unroll
        for (int mt = 0; mt < 4; ++mt)
#pragma unroll
            for (int nt = 0; nt < 4; ++nt)
                acc[mt][nt] = __builtin_amdgcn_mfma_f32_16x16x32_bf16(av[mt], bv[nt], acc[mt][nt], 0, 0, 0);
        if (kc + 1 < KC) {
#pragma unroll
            for (int it = 0; it < 2; ++it)
                *(short8*)&Bsm[p ^ 1][(size_t)(tid + it * 256) * 8] = br2[it];
        }
        __syncthreads();
        p ^= 1;
    }

    float* Gb = G + (size_t)b * 16384;
#pragma unroll
    for (int mt = 0; mt < 4; ++mt)
#pragma unroll
        for (int r = 0; r < 4; ++r) {
            int row = wm * 64 + mt * 16 + lq * 4 + r;
#pragma unroll
            for (int nt = 0; nt < 4; ++nt) {
                int col = wn * 64 + nt * 16 + lr;
                Gb[row * 128 + col] = acc[mt][nt][r];
            }
        }
}

// ---- top-20 from Gram: one wave per (b,n) row; ties -> lower index ----------
__global__ __launch_bounds__(256) void topk_k(const float* __restrict__ G, int* __restrict__ idx) {
    int gw = (blockIdx.x * 256 + threadIdx.x) >> 6;   // 0..2047 = b*128+n
    int lane = threadIdx.x & 63;
    int b = gw >> 7, n = gw & 127;
    const float* Gb = G + (size_t)b * 16384;
    float g0 = Gb[n * 128 + lane];
    float g1 = Gb[n * 128 + 64 + lane];
    float dnn = Gb[n * 129];
    float dm0 = Gb[lane * 129];
    float dm1 = Gb[(64 + lane) * 129];
    float d0 = 2.f * g0 - dnn - dm0;
    float d1 = 2.f * g1 - dnn - dm1;
#pragma unroll
    for (int k = 0; k < 20; ++k) {
        float v; int i;
        if (d1 > d0) { v = d1; i = 64 + lane; } else { v = d0; i = lane; }
#pragma unroll
        for (int off = 1; off < 64; off <<= 1) {
            float ov = __shfl_xor(v, off, 64);
            int   oi = __shfl_xor(i, off, 64);
            if (ov > v || (ov == v && oi < i)) { v = ov; i = oi; }
        }
        if (lane == 0) idx[gw * 20 + k] = i;
        if (i < 64) { if (lane == i) d0 = -3.0e38f; }
        else        { if (lane == i - 64) d1 = -3.0e38f; }
    }
}

// ---- legacy kNN (fallback tiers) --------------------------------------------
template <typename S>
__global__ __launch_bounds__(128) void knn_topk(const S* __restrict__ X, int C, int* __restrict__ idx) {
    int b = blockIdx.x >> 7;
    int n = blockIdx.x & 127;
    int m = threadIdx.x;
    const S* base = X + b * 128;
    float s0 = 0, s1 = 0, q0 = 0, q1 = 0;
    for (int c = 0; c < C; c += 2) {
        const S* p = base + (size_t)c * BN_ALL;
        float xm0 = ld1(p + m),          xn0 = ld1(p + n);
        float xm1 = ld1(p + BN_ALL + m), xn1 = ld1(p + BN_ALL + n);
        s0 += xm0 * xn0; q0 += xm0 * xm0;
        s1 += xm1 * xn1; q1 += xm1 * xm1;
    }
    float inner = s0 + s1;
    float xxm   = q0 + q1;
    __shared__ float xx[128];
    __shared__ float dist[128];
    __shared__ float rv[128];
    __shared__ int   ri[128];
    xx[m] = xxm;
    __syncthreads();
    dist[m] = 2.0f * inner - xx[n] - xxm;
    for (int k = 0; k < 20; k++) {
        __syncthreads();
        rv[m] = dist[m]; ri[m] = m;
        __syncthreads();
        for (int off = 64; off > 0; off >>= 1) {
            if (m < off) {
                float a = rv[m], bv = rv[m + off];
                int ia = ri[m], ib = ri[m + off];
                if (bv > a || (bv == a && ib < ia)) { rv[m] = bv; ri[m] = ib; }
            }
            __syncthreads();
        }
        if (m == 0) { idx[blockIdx.x * 20 + k] = ri[0]; dist[ri[0]] = -3.0e38f; }
    }
}

// ---- weight prepack: f32/bf16 weights -> bf16 in LDS-tile image -------------
__global__ __launch_bounds__(256) void pack_w(const void* __restrict__ w, int ldw,
                                              const void* __restrict__ res, int Cin, int O,
                                              int Mtot, int K, short* __restrict__ out,
                                              const int* __restrict__ dflag) {
    int isb = *dflag;
    int item = blockIdx.x * 256 + threadIdx.x;
    if (item >= Mtot * (K >> 3)) return;
    int m_local = item & 127;
    int rest = item >> 7;            // (tm*KC + kc)*4 + q
    int q = rest & 3; rest >>= 2;
    int KC = K >> 5;
    int kc = rest % KC, tm = rest / KC;
    int grow = tm * 128 + m_local;
    int k = kc * 32 + q * 8;
    const void* src; size_t base; int dif = 0;
    if (grow < O)          { src = w;   base = (size_t)grow * ldw + k; }
    else if (grow < 2 * O) { src = w;   base = (size_t)(grow - O) * ldw + k; dif = 1; }
    else                   { src = res; base = (size_t)(grow - 2 * O) * Cin + k; }
    short8 pk;
#pragma unroll
    for (int j = 0; j < 8; ++j) {
        float v = ldin(src, base + j, isb);
        if (dif) v = ldin(src, base + Cin + j, isb) - v;
        pk[j] = f2bs(v);
    }
    *(short8*)&out[(size_t)item * 8] = pk;
}

// ---- packed-A / k-packed-B bf16 MFMA GEMM, 128x64 tile, BK=32, reg-dbuf -----
__global__ __launch_bounds__(256) void gemm_pk(const short* __restrict__ packA,
                                               const bf16* __restrict__ X, float* __restrict__ Cm, int K,
                                               const void* __restrict__ bnS, const void* __restrict__ bnB,
                                               int act, const int* __restrict__ dflag) {
    __shared__ short Asm[2][4096];   // 128 rows x 32 k (bf16)
    __shared__ short Bsm[2][2048];   // image [(q*64 + c)*8 + j]
    int tid = threadIdx.x;
    int bm  = blockIdx.x << 7;
    int bn0 = blockIdx.y << 6;
    int lane = tid & 63, wv = tid >> 6, wm = wv & 1, wn = wv >> 1;
    int lq = lane >> 4, lr = lane & 15;
    int KC = K >> 5;
    const short* abase = packA + (size_t)blockIdx.x * KC * 4096;
    const short* Xs = (const short*)X;
    int bq = tid >> 6, bc = tid & 63;

    float4v acc[4][2];
#pragma unroll
    for (int i = 0; i < 4; i++)
#pragma unroll
        for (int j = 0; j < 2; j++) acc[i][j] = (float4v){0.f, 0.f, 0.f, 0.f};

    short8 ar[2], brv;

    // prologue: stage kc=0
#pragma unroll
    for (int it = 0; it < 2; ++it)
        ar[it] = *(const short8*)&abase[(size_t)(tid + it * 256) * 8];
    brv = *(const short8*)(Xs + ((size_t)bq * BN_ALL + bn0 + bc) * 8);
#pragma unroll
    for (int it = 0; it < 2; ++it)
        *(short8*)&Asm[0][(size_t)(tid + it * 256) * 8] = ar[it];
    *(short8*)&Bsm[0][(size_t)tid * 8] = brv;
    __syncthreads();

    int p = 0;
    for (int kc = 0; kc < KC; ++kc) {
        if (kc + 1 < KC) {
            const short* ab = abase + (size_t)(kc + 1) * 4096;
#pragma unroll
            for (int it = 0; it < 2; ++it)
                ar[it] = *(const short8*)&ab[(size_t)(tid + it * 256) * 8];
            brv = *(const short8*)(Xs + ((size_t)((kc + 1) * 4 + bq) * BN_ALL + bn0 + bc) * 8);
        }
        short8 av[4], bv[2];
#pragma unroll
        for (int mt = 0; mt < 4; ++mt)
            av[mt] = *(const short8*)&Asm[p][(size_t)((lq << 7) + wm * 64 + mt * 16 + lr) * 8];
#pragma unroll
        for (int nt = 0; nt < 2; ++nt)
            bv[nt] = *(const short8*)&Bsm[p][(size_t)((lq << 6) + wn * 32 + nt * 16 + lr) * 8];
#pragma unroll
        for (int mt = 0; mt < 4; ++mt)
#pragma unroll
            for (int nt = 0; nt < 2; ++nt)
                acc[mt][nt] = __builtin_amdgcn_mfma_f32_16x16x32_bf16(av[mt], bv[nt], acc[mt][nt], 0, 0, 0);
        if (kc + 1 < KC) {
#pragma unroll
            for (int it = 0; it < 2; ++it)
                *(short8*)&Asm[p ^ 1][(size_t)(tid + it * 256) * 8] = ar[it];
            *(short8*)&Bsm[p ^ 1][(size_t)tid * 8] = brv;
        }
        __syncthreads();
        p ^= 1;
    }

    int isb = *dflag;
#pragma unroll
    for (int mt = 0; mt < 4; ++mt) {
#pragma unroll
        for (int r = 0; r < 4; ++r) {
            int row = bm + wm * 64 + mt * 16 + lq * 4 + r;
            float s = 1.f, bb = 0.f;
            if (bnS) { s = ldin(bnS, row, isb); bb = ldin(bnB, row, isb); }
#pragma unroll
            for (int nt = 0; nt < 2; ++nt) {
                int col = bn0 + wn * 32 + nt * 16 + lr;
                float v = acc[mt][nt][r];
                if (bnS) v = v * s + bb;
                if (act) v = lrelu(v);
                Cm[(size_t)row * BN_ALL + col] = v;
            }
        }
    }
}

// ---- R5 fallback GEMM (on-the-fly staging, 128x128, linear layouts) ---------
template <typename S>
__global__ __launch_bounds__(256) void gemm_mfma(const void* __restrict__ w, int ldw,
                                                 const void* __restrict__ res, int Cin, int O,
                                                 const S* __restrict__ X, S* __restrict__ Cm, int K,
                                                 const void* __restrict__ bnS, const void* __restrict__ bnB,
                                                 int act, const int* __restrict__ dflag) {
    int isb = *dflag;
    __shared__ short Asm[4096];
    __shared__ short Bsm[4096];
    int tid = threadIdx.x;
    int bm  = blockIdx.x << 7;
    int bn0 = blockIdx.y << 7;
    int lane = tid & 63, wv = tid >> 6;
    int wm = wv & 1, wn = wv >> 1;
    int lq = lane >> 4, lr = lane & 15;

    float4v acc[4][4];
#pragma unroll
    for (int i = 0; i < 4; i++)
#pragma unroll
        for (int j = 0; j < 4; j++) acc[i][j] = (float4v){0.f, 0.f, 0.f, 0.f};

    for (int k0 = 0; k0 < K; k0 += 32) {
#pragma unroll
        for (int it = 0; it < 2; ++it) {
            int i = tid + it * 256;
            int m = i >> 2, q = i & 3;
            int grow = bm + m;
            const void* asrc; size_t abase; int dif = 0;
            if (grow < O)          { asrc = w;   abase = (size_t)grow * ldw; }
            else if (grow < 2 * O) { asrc = w;   abase = (size_t)(grow - O) * ldw; dif = 1; }
            else                   { asrc = res; abase = (size_t)(grow - 2 * O) * Cin; }
            size_t kk = (size_t)k0 + q * 8;
            short8 pk;
#pragma unroll
            for (int j = 0; j < 8; ++j) {
                float v = ldin(asrc, abase + kk + j, isb);
                if (dif) v = ldin(asrc, abase + Cin + kk + j, isb) - v;
                pk[j] = f2bs(v);
            }
            *(short8*)&Asm[(size_t)(q * 128 + m) * 8] = pk;
        }
#pragma unroll
        for (int it = 0; it < 2; ++it) {
            int i = tid + it * 256;
            int q = i >> 7, c = i & 127;
            const S* xp = X + (size_t)(k0 + q * 8) * BN_ALL + bn0 + c;
            short8 pk;
#pragma unroll
            for (int j = 0; j < 8; ++j) pk[j] = f2bs(ld1(xp + (size_t)j * BN_ALL));
            *(short8*)&Bsm[(size_t)i * 8] = pk;
        }
        __syncthreads();
        short8 av[4], bv[4];
#pragma unroll
        for (int mt = 0; mt < 4; ++mt)
            av[mt] = *(const short8*)&Asm[(size_t)((lq << 7) + wm * 64 + mt * 16 + lr) * 8];
#pragma unroll
        for (int nt = 0; nt < 4; ++nt)
            bv[nt] = *(const short8*)&Bsm[(size_t)((lq << 7) + wn * 64 + nt * 16 + lr) * 8];
#pragma unroll
        for (int mt = 0; mt < 4; ++mt)
#pragma unroll
            for (int nt = 0; nt < 4; ++nt)
                acc[mt][nt] = __builtin_amdgcn_mfma_f32_16x16x32_bf16(av[mt], bv[nt], acc[mt][nt], 0, 0, 0);
        __syncthreads();
    }
#pragma unroll
    for (int mt = 0; mt < 4; ++mt) {
#pragma unroll
        for (int r = 0; r < 4; ++r) {
            int row = bm + wm * 64 + mt * 16 + lq * 4 + r;
            float s = 1.f, bb = 0.f;
            if (bnS) { s = ldin(bnS, row, isb); bb = ldin(bnB, row, isb); }
#pragma unroll
            for (int nt = 0; nt < 4; ++nt) {
                int col = bn0 + wn * 64 + nt * 16 + lr;
                float v = acc[mt][nt][r];
                if (bnS) v = v * s + bb;
                if (act) v = lrelu(v);
                st1(Cm + (size_t)row * BN_ALL + col, v);
            }
        }
    }
}

// ---- gather + k-pool + bn + lrelu; T written IN-PLACE over P row o ----------
template <typename S>
__global__ __launch_bounds__(128) void gather_pool(S* __restrict__ PS, const int* __restrict__ idx,
                                                   const void* __restrict__ bns, const void* __restrict__ bnb,
                                                   float* __restrict__ Mb, int O,
                                                   const int* __restrict__ dflag) {
    int isb = *dflag;
    int o = blockIdx.x, b = blockIdx.y, n = threadIdx.x;
    S* Prow = PS + (size_t)o * BN_ALL + b * 128;
    const int* id = idx + (b * 128 + n) * 20;
    float mx = -3.0e38f, mn = 3.0e38f, sm = 0.f;
#pragma unroll
    for (int k = 0; k < 20; k++) {
        float p = ld1(Prow + id[k]);
        mx = fmaxf(mx, p); mn = fminf(mn, p); sm += p;
    }
    float Sv = ld1(PS + (size_t)(O + o) * BN_ALL + b * 128 + n);
    __shared__ float r1[128], r2[128];
    r1[n] = sm; r2[n] = Sv;
    __syncthreads();                       // all P reads complete before overwrite
    float s = ldin(bns, o, isb), bb = ldin(bnb, o, isb);
    float ext = (s >= 0.f) ? mx : mn;
    st1(Prow + n, lrelu(s * (ext + Sv) + bb));   // T row o (aliases P row o)
    for (int off = 64; off > 0; off >>= 1) {
        if (n < off) { r1[n] += r1[n + off]; r2[n] += r2[n + off]; }
        __syncthreads();
    }
    if (n == 0) Mb[b * O + o] = s * (r1[0] * (1.f / 2560.f) + r2[0] * (1.f / 128.f)) + bb;
}

// ---- SE stage 1: z[b,t] = relu(w1[t,:] . M[b,:]) — one wave per (b,t) -------
__global__ __launch_bounds__(256) void se1_k(const float* __restrict__ Mb, const void* __restrict__ w1,
                                             float* __restrict__ Z, int O, int r,
                                             const int* __restrict__ dflag) {
    int isb = *dflag;
    int gw = (blockIdx.x * 256 + threadIdx.x) >> 6;   // b*r + t
    int lane = threadIdx.x & 63;
    int b = gw / r, t = gw - b * r;
    const float* mv = Mb + (size_t)b * O;
    float acc = 0.f;
    for (int c = lane; c < O; c += 64) acc += ldin(w1, (size_t)t * O + c, isb) * mv[c];
#pragma unroll
    for (int off = 32; off > 0; off >>= 1) acc += __shfl_xor(acc, off, 64);
    if (lane == 0) Z[b * r + t] = fmaxf(acc, 0.f);
}

// ---- SE stage 2: Y[b,o] = sigmoid(w2[o,:] . z[b,:]) — one wave per (b,o) ----
__global__ __launch_bounds__(256) void se2_k(const float* __restrict__ Z, const void* __restrict__ w2,
                                             float* __restrict__ Y, int O, int r,
                                             const int* __restrict__ dflag) {
    int isb = *dflag;
    int gw = (blockIdx.x * 256 + threadIdx.x) >> 6;   // b*O + o
    int lane = threadIdx.x & 63;
    int b = gw / O, o = gw - b * O;
    float acc = 0.f;
    if (lane < r) acc = ldin(w2, (size_t)o * r + lane, isb) * Z[b * r + lane];
#pragma unroll
    for (int off = 32; off > 0; off >>= 1) acc += __shfl_xor(acc, off, 64);
    if (lane == 0) Y[b * O + o] = 1.f / (1.f + expf(-acc));
}

// ---- legacy SE (fallback tiers) ---------------------------------------------
__global__ __launch_bounds__(256) void se_k(const float* __restrict__ Mb, const void* __restrict__ w1,
                                            const void* __restrict__ w2, float* __restrict__ Y, int O, int r,
                                            const int* __restrict__ dflag) {
    int isb = *dflag;
    int b = blockIdx.x, t = threadIdx.x;
    __shared__ float mloc[1024];
    __shared__ float z[64];
    for (int i = t; i < O; i += 256) mloc[i] = Mb[b * O + i];
    __syncthreads();
    if (t < r) {
        float acc = 0.f;
        for (int c = 0; c < O; c++) acc += ldin(w1, (size_t)t * O + c, isb) * mloc[c];
        z[t] = fmaxf(acc, 0.f);
    }
    __syncthreads();
    for (int o = t; o < O; o += 256) {
        float acc = 0.f;
        for (int j = 0; j < r; j++) acc += ldin(w2, (size_t)o * r + j, isb) * z[j];
        Y[b * O + o] = 1.f / (1.f + expf(-acc));
    }
}

// ---- finalize (tier P): x_next = y*T (+res) -> k-packed bf16 slice ----------
__global__ __launch_bounds__(256) void finalize_kp(const float* __restrict__ PS, const float* __restrict__ Y,
                                                   int useR, bf16* __restrict__ Xdst, int O) {
    int item = blockIdx.x * 256 + threadIdx.x;   // og*2048 + bn  (og = o/8)
    int og = item >> 11, bn = item & 2047;
    int b = bn >> 7;
    short8 pk;
#pragma unroll
    for (int j = 0; j < 8; ++j) {
        int r = og * 8 + j;
        float v = Y[b * O + r] * PS[(size_t)r * BN_ALL + bn];
        if (useR) v += PS[(size_t)(2 * O + r) * BN_ALL + bn];
        pk[j] = f2bs(v);
    }
    *(short8*)((short*)Xdst + ((size_t)og * BN_ALL + bn) * 8) = pk;
}

// ---- legacy finalize (fallback tiers, linear layout) ------------------------
template <typename SP, typename SD>
__global__ __launch_bounds__(256) void finalize(const SP* __restrict__ PS, const float* __restrict__ Y,
                                                int useR, SD* __restrict__ Xdst, int O) {
    int tid = blockIdx.x * 256 + threadIdx.x;   // tid = o*2048 + bn
    int o = tid >> 11, bn = tid & 2047;
    int b = bn >> 7;
    float v = Y[b * O + o] * ld1(PS + tid);
    if (useR) v += ld1(PS + (size_t)(2 * O + o) * BN_ALL + bn);
    st1(Xdst + tid, v);
}

// ---- legacy convert (fallback tiers) ----------------------------------------
template <typename S>
__global__ __launch_bounds__(256) void convert_x(const void* __restrict__ x, S* __restrict__ X0,
                                                 const int* __restrict__ dflag) {
    int isb = *dflag;
    int tid = blockIdx.x * 256 + threadIdx.x;
    int c = tid >> 11, bn = tid & 2047;
    int b = bn >> 7, n = bn & 127;
    st1(X0 + tid, ldin(x, (size_t)(b * 512 + c) * 128 + n, isb));
}

// ---- conv5 pool: f[b, m] = max_n, f[b, 2048+m] = mean_n ---------------------
template <typename S>
__global__ __launch_bounds__(128) void pool5(const S* __restrict__ H, float* __restrict__ f) {
    int m = blockIdx.x, b = blockIdx.y, n = threadIdx.x;
    float v = ld1(H + (size_t)m * BN_ALL + b * 128 + n);
    __shared__ float rmx[128], rsm[128];
    rmx[n] = v; rsm[n] = v;
    __syncthreads();
    for (int off = 64; off > 0; off >>= 1) {
        if (n < off) { rmx[n] = fmaxf(rmx[n], rmx[n + off]); rsm[n] += rsm[n + off]; }
        __syncthreads();
    }
    if (n == 0) {
        f[b * 4096 + m] = rmx[0];
        f[b * 4096 + 2048 + m] = rsm[0] * (1.f / 128.f);
    }
}

// ---- head: one wave per (b,o) dot product + optional bias/bn/lrelu ----------
__global__ __launch_bounds__(256) void head_k(const float* __restrict__ in, const void* __restrict__ W,
                                              const void* __restrict__ bias, const void* __restrict__ bns,
                                              const void* __restrict__ bnb, float* __restrict__ outf,
                                              void* __restrict__ outb, int Kd, int Od, int act,
                                              const int* __restrict__ dflag) {
    int isb = *dflag;
    int gw = (blockIdx.x * 256 + threadIdx.x) >> 6;
    int lane = threadIdx.x & 63;
    if (gw >= 16 * Od) return;
    int b = gw / Od, o = gw - b * Od;
    const float* iv = in + b * Kd;
    float acc = 0.f;
    for (int k = lane; k < Kd; k += 64) acc += iv[k] * ldin(W, (size_t)o * Kd + k, isb);
    for (int off = 32; off > 0; off >>= 1) acc += __shfl_xor(acc, off, 64);
    if (lane == 0) {
        float v = acc;
        if (bias) v += ldin(bias, o, isb);
        if (bns) v = v * ldin(bns, o, isb) + ldin(bnb, o, isb);
        if (act) v = lrelu(v);
        if (outb) {
            if (isb) ((bf16*)outb)[gw] = __float2bfloat16(v);
            else     ((float*)outb)[gw] = v;
        } else outf[gw] = v;
    }
}

// ---- ws-too-small signal ----------------------------------------------------
__global__ __launch_bounds__(256) void zero_out(bf16* o, int n) {
    int i = blockIdx.x * 256 + threadIdx.x;
    if (i < n) o[i] = __float2bfloat16(0.f);
}

// ---------------------------------------------------------------------------
#define UNPACK_INPUTS()                                                     \
    const void* x_in   = d_in[0];                                           \
    const void* conv1w = d_in[1];  const void* conv2w = d_in[2];            \
    const void* conv3w = d_in[3];  const void* conv4w = d_in[4];            \
    const void* conv5w = d_in[5];                                           \
    const void* bn1s = d_in[6],  * bn1b = d_in[7];                          \
    const void* bn2s = d_in[8],  * bn2b = d_in[9];                          \
    const void* bn3s = d_in[10], * bn3b = d_in[11];                         \
    const void* bn4s = d_in[12], * bn4b = d_in[13];                         \
    const void* bn5s = d_in[14], * bn5b = d_in[15];                         \
    const void* se1w1 = d_in[16], * se1w2 = d_in[17];                       \
    const void* se2w1 = d_in[18], * se2w2 = d_in[19];                       \
    const void* se3w1 = d_in[20], * se3w2 = d_in[21];                       \
    const void* se4w1 = d_in[22], * se4w2 = d_in[23];                       \
    const void* res1w = d_in[24]; const void* res2w = d_in[25];             \
    const void* res3w = d_in[26]; const void* lin1w = d_in[27];             \
    const void* bn6s = d_in[28], * bn6b = d_in[29];                         \
    const void* lin2w = d_in[30], * lin2b = d_in[31];                       \
    const void* bn7s = d_in[32], * bn7b = d_in[33];                         \
    const void* lin3w = d_in[34], * lin3b = d_in[35];

// ---- Tier P: packed weights, f32 PS, k-packed bf16 activations --------------
static void run_net_packed(void* const* d_in, void* d_out, void* d_ws, hipStream_t stream) {
    UNPACK_INPUTS();
    float* WS = (float*)d_ws;
    float* PS   = WS;                              // 3072 x 2048 f32 (gemm out / T / conv5 H)
    bf16*  XC   = (bf16*)(WS + 6291456);           // 3072 x 2048 bf16 k-packed (x1|x2|x3|x4)
    short* PACK = (short*)(WS + 12582912);         // up to 6,291,456 shorts
    float* MB = WS + 15728640;
    float* YB = MB + 16384;
    float* FB = YB + 16384;
    float* F1 = FB + 65536;
    float* F2 = F1 + 8192;
    int* IDX  = (int*)(F2 + 4096);
    int* DFLAG = IDX + 40960;
    float* ZB = (float*)(DFLAG + 16);              // 1024 floats
    bf16*  X0 = (bf16*)(PS + (size_t)2048 * BN_ALL);  // PS rows 2048.. (block 1 only)
    float* GRAM = PS;                              // PS rows 0..127 during kNN
    bf16* X1 = XC;
    bf16* X2 = XC + (size_t)512 * BN_ALL;
    bf16* X3 = XC + (size_t)1024 * BN_ALL;
    bf16* X4 = XC + (size_t)2048 * BN_ALL;

    detect_dtype<<<1, 256, 0, stream>>>(x_in, DFLAG);
    convert_kp<<<512, 256, 0, stream>>>(x_in, X0, DFLAG);

    // block 1: Cin=512, O=512, Mtot=1024, K=512, r=32
    gram_k<<<16, 256, 0, stream>>>(X0, 512, GRAM);
    topk_k<<<512, 256, 0, stream>>>(GRAM, IDX);
    pack_w<<<256, 256, 0, stream>>>(conv1w, 1024, nullptr, 512, 512, 1024, 512, PACK, DFLAG);
    gemm_pk<<<dim3(8, 32), 256, 0, stream>>>(PACK, X0, PS, 512, nullptr, nullptr, 0, DFLAG);
    gather_pool<float><<<dim3(512, 16), 128, 0, stream>>>(PS, IDX, bn1s, bn1b, MB, 512, DFLAG);
    se1_k<<<128, 256, 0, stream>>>(MB, se1w1, ZB, 512, 32, DFLAG);
    se2_k<<<2048, 256, 0, stream>>>(ZB, se1w2, YB, 512, 32, DFLAG);
    finalize_kp<<<512, 256, 0, stream>>>(PS, YB, 0, X1, 512);

    // block 2: Mtot=1536, K=512, res1, r=32
    gram_k<<<16, 256, 0, stream>>>(X1, 512, GRAM);
    topk_k<<<512, 256, 0, stream>>>(GRAM, IDX);
    pack_w<<<384, 256, 0, stream>>>(conv2w, 1024, res1w, 512, 512, 1536, 512, PACK, DFLAG);
    gemm_pk<<<dim3(12, 32), 256, 0, stream>>>(PACK, X1, PS, 512, nullptr, nullptr, 0, DFLAG);
    gather_pool<float><<<dim3(512, 16), 128, 0, stream>>>(PS, IDX, bn2s, bn2b, MB, 512, DFLAG);
    se1_k<<<128, 256, 0, stream>>>(MB, se2w1, ZB, 512, 32, DFLAG);
    se2_k<<<2048, 256, 0, stream>>>(ZB, se2w2, YB, 512, 32, DFLAG);
    finalize_kp<<<512, 256, 0, stream>>>(PS, YB, 1, X2, 512);

    // block 3: O=1024, Mtot=3072, K=512, res2, r=64
    gram_k<<<16, 256, 0, stream>>>(X2, 512, GRAM);
    topk_k<<<512, 256, 0, stream>>>(GRAM, IDX);
    pack_w<<<768, 256, 0, stream>>>(conv3w, 1024, res2w, 512, 1024, 3072, 512, PACK, DFLAG);
    gemm_pk<<<dim3(24, 32), 256, 0, stream>>>(PACK, X2, PS, 512, nullptr, nullptr, 0, DFLAG);
    gather_pool<float><<<dim3(1024, 16), 128, 0, stream>>>(PS, IDX, bn3s, bn3b, MB, 1024, DFLAG);
    se1_k<<<256, 256, 0, stream>>>(MB, se3w1, ZB, 1024, 64, DFLAG);
    se2_k<<<4096, 256, 0, stream>>>(ZB, se3w2, YB, 1024, 64, DFLAG);
    finalize_kp<<<1024, 256, 0, stream>>>(PS, YB, 1, X3, 1024);

    // block 4: O=1024, Mtot=3072, K=1024, res3, r=64
    gram_k<<<16, 256, 0, stream>>>(X3, 1024, GRAM);
    topk_k<<<512, 256, 0, stream>>>(GRAM, IDX);
    pack_w<<<1536, 256, 0, stream>>>(conv4w, 2048, res3w, 1024, 1024, 3072, 1024, PACK, DFLAG);
    gemm_pk<<<dim3(24, 32), 256, 0, stream>>>(PACK, X3, PS, 1024, nullptr, nullptr, 0, DFLAG);
    gather_pool<float><<<dim3(1024, 16), 128, 0, stream>>>(PS, IDX, bn4s, bn4b, MB, 1024, DFLAG);
    se1_k<<<256, 256, 0, stream>>>(MB, se4w1, ZB, 1024, 64, DFLAG);
    se2_k<<<4096, 256, 0, stream>>>(ZB, se4w2, YB, 1024, 64, DFLAG);
    finalize_kp<<<1024, 256, 0, stream>>>(PS, YB, 1, X4, 1024);

    // conv5: Mtot=2048, K=3072, bn5+lrelu
    pack_w<<<3072, 256, 0, stream>>>(conv5w, 3072, nullptr, 3072, 2048, 2048, 3072, PACK, DFLAG);
    gemm_pk<<<dim3(16, 32), 256, 0, stream>>>(PACK, XC, PS, 3072, bn5s, bn5b, 1, DFLAG);
    pool5<float><<<dim3(2048, 16), 128, 0, stream>>>(PS, FB);

    head_k<<<2048, 256, 0, stream>>>(FB, lin1w, nullptr, bn6s, bn6b, F1, nullptr, 4096, 512, 1, DFLAG);
    head_k<<<1024, 256, 0, stream>>>(F1, lin2w, lin2b, bn7s, bn7b, F2, nullptr, 512, 256, 1, DFLAG);
    head_k<<<160, 256, 0, stream>>>(F2, lin3w, lin3b, nullptr, nullptr, nullptr, d_out, 256, 40, 0, DFLAG);
}

// ---- Tier A/B fallback (R5 path, linear layouts) ----------------------------
template <typename S>
static void run_net(void* const* d_in, void* d_out, void* d_ws, hipStream_t stream) {
    UNPACK_INPUTS();
    const size_t RC = (size_t)3072 * BN_ALL;
    S* PS = (S*)d_ws;
    S* XC = PS + RC;
    S* X0 = PS + (size_t)2048 * BN_ALL;
    float* MB = (float*)(XC + RC);
    float* YB = MB + 16 * 1024;
    float* FB = YB + 16 * 1024;
    float* F1 = FB + 16 * 4096;
    float* F2 = F1 + 16 * 512;
    int* IDX  = (int*)(F2 + 16 * 256);
    int* DFLAG = IDX + 16 * 128 * 20;

    S* X1 = XC;
    S* X2 = XC + (size_t)512 * BN_ALL;
    S* X3 = XC + (size_t)1024 * BN_ALL;
    S* X4 = XC + (size_t)2048 * BN_ALL;

    detect_dtype<<<1, 256, 0, stream>>>(x_in, DFLAG);
    convert_x<S><<<4096, 256, 0, stream>>>(x_in, X0, DFLAG);

    knn_topk<S><<<2048, 128, 0, stream>>>(X0, 512, IDX);
    gemm_mfma<S><<<dim3(8, 16), 256, 0, stream>>>(conv1w, 1024, nullptr, 512, 512, X0, PS, 512, nullptr, nullptr, 0, DFLAG);
    gather_pool<S><<<dim3(512, 16), 128, 0, stream>>>(PS, IDX, bn1s, bn1b, MB, 512, DFLAG);
    se_k<<<16, 256, 0, stream>>>(MB, se1w1, se1w2, YB, 512, 32, DFLAG);
    finalize<S, S><<<4096, 256, 0, stream>>>(PS, YB, 0, X1, 512);

    knn_topk<S><<<2048, 128, 0, stream>>>(X1, 512, IDX);
    gemm_mfma<S><<<dim3(12, 16), 256, 0, stream>>>(conv2w, 1024, res1w, 512, 512, X1, PS, 512, nullptr, nullptr, 0, DFLAG);
    gather_pool<S><<<dim3(512, 16), 128, 0, stream>>>(PS, IDX, bn2s, bn2b, MB, 512, DFLAG);
    se_k<<<16, 256, 0, stream>>>(MB, se2w1, se2w2, YB, 512, 32, DFLAG);
    finalize<S, S><<<4096, 256, 0, stream>>>(PS, YB, 1, X2, 512);

    knn_topk<S><<<2048, 128, 0, stream>>>(X2, 512, IDX);
    gemm_mfma<S><<<dim3(24, 16), 256, 0, stream>>>(conv3w, 1024, res2w, 512, 1024, X2, PS, 512, nullptr, nullptr, 0, DFLAG);
    gather_pool<S><<<dim3(1024, 16), 128, 0, stream>>>(PS, IDX, bn3s, bn3b, MB, 1024, DFLAG);
    se_k<<<16, 256, 0, stream>>>(MB, se3w1, se3w2, YB, 1024, 64, DFLAG);
    finalize<S, S><<<8192, 256, 0, stream>>>(PS, YB, 1, X3, 1024);

    knn_topk<S><<<2048, 128, 0, stream>>>(X3, 1024, IDX);
    gemm_mfma<S><<<dim3(24, 16), 256, 0, stream>>>(conv4w, 2048, res3w, 1024, 1024, X3, PS, 1024, nullptr, nullptr, 0, DFLAG);
    gather_pool<S><<<dim3(1024, 16), 128, 0, stream>>>(PS, IDX, bn4s, bn4b, MB, 1024, DFLAG);
    se_k<<<16, 256, 0, stream>>>(MB, se4w1, se4w2, YB, 1024, 64, DFLAG);
    finalize<S, S><<<8192, 256, 0, stream>>>(PS, YB, 1, X4, 1024);

    gemm_mfma<S><<<dim3(16, 16), 256, 0, stream>>>(conv5w, 3072, nullptr, 3072, 2048, XC, PS, 3072, bn5s, bn5b, 1, DFLAG);
    pool5<S><<<dim3(2048, 16), 128, 0, stream>>>(PS, FB);

    head_k<<<2048, 256, 0, stream>>>(FB, lin1w, nullptr, bn6s, bn6b, F1, nullptr, 4096, 512, 1, DFLAG);
    head_k<<<1024, 256, 0, stream>>>(F1, lin2w, lin2b, bn7s, bn7b, F2, nullptr, 512, 256, 1, DFLAG);
    head_k<<<160, 256, 0, stream>>>(F2, lin3w, lin3b, nullptr, nullptr, nullptr, d_out, 256, 40, 0, DFLAG);
}

extern "C" void kernel_launch(void* const* d_in, const int* in_sizes, int n_in,
                              void* d_out, int out_size, void* d_ws, size_t ws_size,
                              hipStream_t stream) {
    const size_t SMALL = (16 * 1024 + 16 * 1024 + 16 * 4096 + 16 * 512 + 16 * 256) * 4
                       + 16 * 128 * 20 * 4 + 8192;
    const size_t NEED_PACKED = (size_t)15728640 * 4 + SMALL;
    const size_t NEED_F32    = 2 * ((size_t)3072 * BN_ALL * 4) + SMALL;
    const size_t NEED_BF16   = 2 * ((size_t)3072 * BN_ALL * 2) + SMALL;
    if (ws_size >= NEED_PACKED) {
        run_net_packed(d_in, d_out, d_ws, stream);
    } else if (ws_size >= NEED_F32) {
        run_net<float>(d_in, d_out, d_ws, stream);
    } else if (ws_size >= NEED_BF16) {
        run_net<bf16>(d_in, d_out, d_ws, stream);
    } else {
        zero_out<<<3, 256, 0, stream>>>((bf16*)d_out, out_size);
    }
}